// Round 10
// baseline (87.981 us; speedup 1.0000x reference)
//
#include <hip/hip_runtime.h>
#include <hip/hip_bf16.h>

// Problem constants (B=2,S=1024,D=512,H=2048,E=8,K=2)
#define TB   2048
#define DD   512
#define HH   2048
#define EE   8
#define TK   4096   // TB*KSEL

typedef __attribute__((ext_vector_type(8))) __bf16 bf16x8;
typedef __attribute__((ext_vector_type(4))) float  f32x4;
typedef __attribute__((ext_vector_type(4))) unsigned int u32x4;

#define CONTRIB_ELEMS ((size_t)TK * DD)   // per-ksplit contrib (bf16)
#define KSPLIT1 2                         // pass-1 K-split, ks-interleaved (R6-proven best)

__device__ __forceinline__ unsigned short f2bf(float f) {
  return __builtin_bit_cast(unsigned short, (__bf16)f);   // native v_cvt (RNE)
}
__device__ __forceinline__ float bf2f(unsigned short h) {
  union { unsigned u; float f; } c; c.u = (unsigned)h << 16; return c.f;
}

// ---------------- routing ----------------
__global__ void route_kernel(const int* __restrict__ idx, const float* __restrict__ wts,
                             int* cnt, int* offs, int* rowt, int* pos, float* wrow) {
  __shared__ int s_cnt[EE], s_off[EE], s_fill[EE];
  int tid = threadIdx.x;
  if (tid < EE) s_cnt[tid] = 0;
  __syncthreads();
  for (int i = tid; i < TK; i += 256) atomicAdd(&s_cnt[idx[i]], 1);
  __syncthreads();
  if (tid == 0) {
    int acc = 0;
    for (int e = 0; e < EE; ++e) { s_off[e] = acc; acc += s_cnt[e]; s_fill[e] = s_off[e]; }
  }
  __syncthreads();
  for (int i = tid; i < TK; i += 256) {
    int e = idx[i];
    int r = atomicAdd(&s_fill[e], 1);
    rowt[r] = i;
    pos[i]  = r;
    wrow[r] = wts[i];
  }
  if (tid < EE) { cnt[tid] = s_cnt[tid]; offs[tid] = s_off[tid]; }
}

// ---------------- prep: gather-x + keys transpose ----------------
// blocks [0,1024): gather x rows -> Xg (bf16, routed order)
// blocks [1024,3072): keys [D][E][H] f32 -> kT [E][H][D] bf16   (64x64 tiles)
// (values transpose fused into pass0's grid — it is not needed until pass1)
__global__ __launch_bounds__(256) void prep_kernel(
    const float* __restrict__ x, const int* __restrict__ rowt, unsigned short* __restrict__ Xg,
    const float* __restrict__ keys, unsigned short* __restrict__ kT) {
  int bid = blockIdx.x;
  int tid = threadIdx.x;
  if (bid < 1024) {
    int i = bid * 256 + tid;
    int r = i >> 6;            // DD/8 = 64 chunks per row
    int c = i & 63;
    int t = rowt[r] >> 1;      // KSEL = 2
    const float4* src = (const float4*)(x + (size_t)t * DD + c * 8);
    float4 a = src[0], b = src[1];
    unsigned short res[8];
    res[0]=f2bf(a.x); res[1]=f2bf(a.y); res[2]=f2bf(a.z); res[3]=f2bf(a.w);
    res[4]=f2bf(b.x); res[5]=f2bf(b.y); res[6]=f2bf(b.z); res[7]=f2bf(b.w);
    *(uint4*)(Xg + (size_t)r * DD + c * 8) = *(uint4*)res;
    return;
  }
  __shared__ unsigned short tt[64][66];
  // keys: k=d (8 blocks), n=h (32 blocks), 256 blocks/expert
  int rel = bid - 1024; int e = rel >> 8; int rem = rel & 255;
  int k0 = (rem >> 5) * 64, n0 = (rem & 31) * 64;
  #pragma unroll
  for (int it = 0; it < 4; ++it) {
    int idx = tid + it * 256;
    int r  = idx >> 4;
    int c4 = idx & 15;
    float4 v = *(const float4*)(keys + (size_t)(k0 + r) * (EE * HH) + (size_t)e * HH + n0 + c4 * 4);
    unsigned short q[4] = {f2bf(v.x), f2bf(v.y), f2bf(v.z), f2bf(v.w)};
    *(uint2*)&tt[r][c4 * 4] = *(uint2*)q;
  }
  __syncthreads();
  #pragma unroll
  for (int it = 0; it < 2; ++it) {
    int idx = tid + it * 256;
    int n  = idx >> 3;
    int kc = (idx & 7) * 8;
    unsigned short q[8];
    #pragma unroll
    for (int i = 0; i < 8; ++i) q[i] = tt[kc + i][n];
    *(uint4*)(kT + ((size_t)e * HH + n0 + n) * DD + k0 + kc) = *(uint4*)q;
  }
}

// ---------------- values transpose (fused into pass0 grid, LEADING blocks) ----------------
// Leading = prefetch (R6 vs R8 A/B: leading beats trailing by ~4 us).
// nontemporal LOAD (f32 values, read-once stream); NORMAL store so vT stays cached for p1.
__device__ __forceinline__ void vt_transpose(unsigned short* smem, const float* __restrict__ values,
                                             unsigned short* __restrict__ vT, int bid, int tid) {
  // values [H][E][D] f32 -> vT [E][D][H] bf16 ; 2048 blocks, 256/expert (e = bid&7 -> own XCD)
  int e = bid & 7, rem = bid >> 3;
  int k0 = (rem >> 3) * 64;   // h-block (32)
  int n0 = (rem & 7) * 64;    // d-block (8)
  unsigned short (*tt)[66] = (unsigned short(*)[66])smem;
  #pragma unroll
  for (int it = 0; it < 4; ++it) {
    int idx = tid + it * 256;
    int r = idx >> 4, c4 = idx & 15;
    const f32x4* sp = (const f32x4*)(values + (size_t)(k0 + r) * (EE * DD) + (size_t)e * DD + n0 + c4 * 4);
    f32x4 v = __builtin_nontemporal_load(sp);
    unsigned short q[4] = {f2bf(v.x), f2bf(v.y), f2bf(v.z), f2bf(v.w)};
    *(uint2*)&tt[r][c4 * 4] = *(uint2*)q;
  }
  __syncthreads();
  #pragma unroll
  for (int it = 0; it < 2; ++it) {
    int idx = tid + it * 256;
    int n = idx >> 3;
    int kc = (idx & 7) * 8;
    unsigned short q[8];
    #pragma unroll
    for (int i = 0; i < 8; ++i) q[i] = tt[kc + i][n];
    *(uint4*)(vT + ((size_t)e * DD + n0 + n) * HH + k0 + kc) = *(uint4*)q;
  }
}

// ---------------- swizzled global->LDS staging (linear dest, pre-swizzled source) ----------------
// Tile: ROWS x 64 bf16 (128 B/row). LDS(row, slot) holds global (row, slot^(row&7)).
template<int ROWS>
__device__ __forceinline__ void stage_swz(const char* src, int src_stride,
                                          unsigned short* lds, int wave, int lane) {
  constexpr int PW = ROWS * 128 / 1024 / 4;   // insts per wave (4 waves)
  #pragma unroll
  for (int j = 0; j < PW; ++j) {
    int base = (wave * PW + j) * 1024;
    int o = base + lane * 16;
    int row  = o >> 7;
    int slot = (o >> 4) & 7;
    const char* g = src + (size_t)row * src_stride + ((slot ^ (row & 7)) << 4);
    __builtin_amdgcn_global_load_lds(
        (const __attribute__((address_space(1))) unsigned*)g,
        (__attribute__((address_space(3))) unsigned*)((char*)lds + base), 16, 0, 0);
  }
}

// ---------------- grouped expert GEMM body, 2-phase dbuf ----------------
// PASS 0: hidden = gelu(Xg @ kT[e]^T + key_bias[e])   bf16 out, K=512, N=2048, 128x128 tile
//   LDS-BW model: bytes/MFLOP = 22.9 at 128^2 vs 45.7 at 64^2 -> ~2x GEMM speedup
//   (R1 measured-by-subtraction ~13-18 us; R1's regression was the phase-serialized p1).
// PASS 1: contrib = (hid @ vT[e]^T [+ bias]) * w      bf16 out, K=2048 (split 2, INTERLEAVED), 64x64
// Per-XCD ordering: e = XCD; within XCD rem = (mblk, xblk, ks), mblk-major so active
// (mblk*BM < n_e) blocks are first and inactive ones exit immediately; ks fastest.
template<int BM, int BN, int PASS, int KSPLIT>
__device__ __forceinline__ void ffn_gemm_body(
    int bid, unsigned short* smem,
    const unsigned short* __restrict__ Aall, const unsigned short* __restrict__ Bw,
    const float* __restrict__ bias,
    const int* __restrict__ cnt, const int* __restrict__ offs,
    const float* __restrict__ wrow,
    unsigned short* __restrict__ outA, unsigned short* __restrict__ outB)
{
  constexpr int KDIM = (PASS == 0) ? DD : HH;
  constexpr int NDIM = (PASS == 0) ? HH : DD;
  constexpr int KLEN = KDIM / KSPLIT;
  constexpr int NT   = KLEN / 64;
  constexpr int NX   = NDIM / BN;
  constexpr int NY   = TK / BM;
  constexpr int PER_E = NY * NX * KSPLIT;     // blocks per expert
  constexpr int NWG  = EE * PER_E;
  constexpr int WM = BM / 2, WN = BN / 2;
  constexpr int FM = WM / 16, FN = WN / 16;

  // bijective XCD-chunk swizzle (EE==8): XCD owns expert e = bid&7
  int swz = (bid & 7) * (NWG / 8) + (bid >> 3);
  int e   = swz / PER_E;
  int rem = swz % PER_E;
  int mblk = rem / (NX * KSPLIT);
  int r2   = rem % (NX * KSPLIT);
  int xblk = r2 / KSPLIT;
  int ks   = r2 % KSPLIT;

  const int n_e = cnt[e];
  if (mblk * BM >= n_e) return;
  const int off_e = offs[e];
  const int bn = xblk * BN;

  unsigned short* Sb0 = smem;
  unsigned short* Sb1 = smem + (BM + BN) * 64;

  const int tid  = threadIdx.x;
  const int lane = tid & 63;
  const int wave = tid >> 6;
  const int wm = wave >> 1, wn = wave & 1;
  const int lr = lane & 15;
  const int kg = lane >> 4;

  const char* Ab = (const char*)(Aall + (size_t)(off_e + mblk * BM) * KDIM + ks * KLEN);
  const char* Bb = (const char*)(Bw + ((size_t)e * NDIM + bn) * KDIM + ks * KLEN);

  f32x4 acc[FM][FN] = {};

  auto STAGE = [&](unsigned short* buf, int kt) {
    stage_swz<BM>(Ab + kt * 128, KDIM * 2, buf, wave, lane);
    stage_swz<BN>(Bb + kt * 128, KDIM * 2, buf + BM * 64, wave, lane);
  };
  auto COMPUTE = [&](const unsigned short* buf) {
    const char* As = (const char*)buf;
    const char* Bs = (const char*)(buf + BM * 64);
    #pragma unroll
    for (int kss = 0; kss < 2; ++kss) {
      bf16x8 af[FM], bfv[FN];
      #pragma unroll
      for (int fm = 0; fm < FM; ++fm) {
        int r = wm * WM + fm * 16 + lr;
        int sl = (kss * 4 + kg) ^ (r & 7);
        af[fm] = *(const bf16x8*)(As + r * 128 + (sl << 4));
      }
      #pragma unroll
      for (int fn = 0; fn < FN; ++fn) {
        int r = wn * WN + fn * 16 + lr;
        int sl = (kss * 4 + kg) ^ (r & 7);
        bfv[fn] = *(const bf16x8*)(Bs + r * 128 + (sl << 4));
      }
      #pragma unroll
      for (int fm = 0; fm < FM; ++fm)
        #pragma unroll
        for (int fn = 0; fn < FN; ++fn)
          acc[fm][fn] = __builtin_amdgcn_mfma_f32_16x16x32_bf16(af[fm], bfv[fn], acc[fm][fn], 0, 0, 0);
    }
  };

  STAGE(Sb0, 0);
  __syncthreads();
  #pragma unroll 2
  for (int kt = 0; kt < NT; kt += 2) {
    if (kt + 1 < NT) STAGE(Sb1, kt + 1);   // issue next-tile loads BEFORE compute
    COMPUTE(Sb0);
    __syncthreads();
    if (kt + 2 < NT) STAGE(Sb0, kt + 2);
    COMPUTE(Sb1);
    __syncthreads();
  }

  // epilogue
  const int rq = kg * 4;
  #pragma unroll
  for (int fm = 0; fm < FM; ++fm) {
    int row0 = mblk * BM + wm * WM + fm * 16 + rq;
    #pragma unroll
    for (int fn = 0; fn < FN; ++fn) {
      int col = bn + wn * WN + fn * 16 + lr;
      float bs = (PASS == 0 || ks == 0) ? bias[e * NDIM + col] : 0.f;
      #pragma unroll
      for (int i = 0; i < 4; ++i) {
        int rl = row0 + i;
        if (rl < n_e) {
          float v = acc[fm][fn][i] + bs;
          if (PASS == 0) {
            float u = 0.7978845608f * (v + 0.044715f * v * v * v);
            float g = v / (1.f + __expf(-2.f * u));
            outA[(size_t)(off_e + rl) * HH + col] = f2bf(g);
          } else {
            float w = wrow[off_e + rl];
            outB[ks * CONTRIB_ELEMS + (size_t)(off_e + rl) * DD + col] = f2bf(v * w);
          }
        }
      }
    }
  }
}

// Distinct names so rocprof attributes time per pass.
// p0: 2048 vt blocks LEADING (prefetch), then 4096 128x128 GEMM blocks
//     (64 active/XCD = 2/CU at 2/CU resident; LDS 64 KB, VGPR ~88).
__global__ __launch_bounds__(256, 2) void ffn_gemm_p0(
    const unsigned short* __restrict__ Aall, const unsigned short* __restrict__ Bw,
    const float* __restrict__ bias, const int* __restrict__ cnt, const int* __restrict__ offs,
    const float* __restrict__ wrow, unsigned short* __restrict__ outA,
    const float* __restrict__ values, unsigned short* __restrict__ vT) {
  __shared__ __align__(1024) unsigned short smem[2 * (128 + 128) * 64];
  int bid = blockIdx.x;
  if (bid < 2048) { vt_transpose(smem, values, vT, bid, threadIdx.x); return; }
  ffn_gemm_body<128, 128, 0, 1>(bid - 2048, smem, Aall, Bw, bias, cnt, offs, wrow,
                                outA, nullptr);
}
// p1: 64x64, KSPLIT=2 interleaved (R6-proven), 5 blocks/CU resident, ~128 active/XCD.
__global__ __launch_bounds__(256, 5) void ffn_gemm_p1(
    const unsigned short* __restrict__ Aall, const unsigned short* __restrict__ Bw,
    const float* __restrict__ bias, const int* __restrict__ cnt, const int* __restrict__ offs,
    const float* __restrict__ wrow, unsigned short* __restrict__ outB) {
  __shared__ __align__(1024) unsigned short smem[2 * (64 + 64) * 64];
  ffn_gemm_body<64, 64, 1, KSPLIT1>(blockIdx.x, smem, Aall, Bw, bias, cnt, offs, wrow,
                                    nullptr, outB);
}

// ---------------- combine: out[t] = sum over KSPLIT1 parts and both selected rows ----------------
__global__ void combine(const unsigned short* __restrict__ contrib, const int* __restrict__ pos,
                        float* __restrict__ out) {
  int i = blockIdx.x * blockDim.x + threadIdx.x;   // TB * 64 threads
  int t = i >> 6;
  int c = i & 63;              // 8-elem chunk
  int r0 = pos[t * 2], r1 = pos[t * 2 + 1];
  float o[8] = {0,0,0,0,0,0,0,0};
  #pragma unroll
  for (int p = 0; p < KSPLIT1; ++p) {
    const unsigned short* base = contrib + (size_t)p * CONTRIB_ELEMS;
    union { uint4 q; unsigned short h[8]; } a, b;
    a.q = *(const uint4*)(base + (size_t)r0 * DD + c * 8);
    b.q = *(const uint4*)(base + (size_t)r1 * DD + c * 8);
    #pragma unroll
    for (int j = 0; j < 8; ++j)
      o[j] += bf2f(a.h[j]) + bf2f(b.h[j]);
  }
  float* dst = out + (size_t)t * DD + c * 8;
  *(float4*)dst       = *(float4*)&o[0];
  *(float4*)(dst + 4) = *(float4*)&o[4];
}

extern "C" void kernel_launch(void* const* d_in, const int* in_sizes, int n_in,
                              void* d_out, int out_size, void* d_ws, size_t ws_size,
                              hipStream_t stream) {
  const float* x          = (const float*)d_in[0];
  const int*   indices    = (const int*)d_in[1];
  const float* weights    = (const float*)d_in[2];
  const float* keys       = (const float*)d_in[3];
  const float* key_bias   = (const float*)d_in[4];
  const float* values     = (const float*)d_in[5];
  const float* value_bias = (const float*)d_in[6];
  float* out = (float*)d_out;

  char* ws = (char*)d_ws;
  int*   cnt  = (int*)(ws);
  int*   offs = (int*)(ws + 256);
  int*   rowt = (int*)(ws + 512);
  int*   pos  = (int*)(ws + 512 + 4 * TK);
  float* wrow = (float*)(ws + 512 + 8 * TK);
  // Xg:  64 KB .. +4.3 MB (+slack)   hid: 8 MB .. +17.0 MB (+slack)
  // kT:  26 MB .. +16.8 MB (dead after pass0; contrib overlays it)
  // vT:  43 MB .. +16.8 MB           contrib: 26 MB .. +8.4 MB (2 x bf16 parts)
  unsigned short* Xg      = (unsigned short*)(ws + (64u << 10));
  unsigned short* hid     = (unsigned short*)(ws + (8u  << 20));
  unsigned short* kT      = (unsigned short*)(ws + (26u << 20));
  unsigned short* vT      = (unsigned short*)(ws + (43u << 20));
  unsigned short* contrib = (unsigned short*)(ws + (26u << 20));

  route_kernel<<<1, 256, 0, stream>>>(indices, weights, cnt, offs, rowt, pos, wrow);
  // prep: 1024 gather blocks + 2048 keys-transpose blocks
  prep_kernel<<<3072, 256, 0, stream>>>(x, rowt, Xg, keys, kT);

  // pass 0: 2048 leading vt blocks (values streamed via nt-load) + 4096 128x128 GEMM wgs
  ffn_gemm_p0<<<2048 + EE * (TK/128) * (HH/128), 256, 0, stream>>>(
      Xg, kT, key_bias, cnt, offs, wrow, hid, values, vT);
  // pass 1: 64x64, K-split 2 INTERLEAVED (ks fastest)
  ffn_gemm_p1<<<EE * (TK/64) * (DD/64) * KSPLIT1, 256, 0, stream>>>(
      hid, vT, value_bias, cnt, offs, wrow, contrib);
  combine<<<(TB * 64) / 256, 256, 0, stream>>>(contrib, pos, out);
}

// Round 11
// 86.299 us; speedup vs baseline: 1.0195x; 1.0195x over previous
//
#include <hip/hip_runtime.h>
#include <hip/hip_bf16.h>

// Problem constants (B=2,S=1024,D=512,H=2048,E=8,K=2)
#define TB   2048
#define DD   512
#define HH   2048
#define EE   8
#define TK   4096   // TB*KSEL

typedef __attribute__((ext_vector_type(8))) __bf16 bf16x8;
typedef __attribute__((ext_vector_type(4))) float  f32x4;
typedef __attribute__((ext_vector_type(4))) unsigned int u32x4;

#define CONTRIB_ELEMS ((size_t)TK * DD)   // per-ksplit contrib (bf16)
#define KSPLIT1 2                         // pass-1 K-split, ks-interleaved (R6-proven best)

__device__ __forceinline__ unsigned short f2bf(float f) {
  return __builtin_bit_cast(unsigned short, (__bf16)f);   // native v_cvt (RNE)
}
__device__ __forceinline__ float bf2f(unsigned short h) {
  union { unsigned u; float f; } c; c.u = (unsigned)h << 16; return c.f;
}

// ---------------- prep: route + gather-x + keys transpose, ONE launch ----------------
// bid 0        : routing (histogram + stable bucket fill). Ends with threadfence +
//                device-scope flag=1 release.
// bids [1,1025): gather x rows -> Xg (bf16, routed order). Spin-acquire on flag, then
//                read rowt via device-scope atomic loads (4 per block, via LDS).
// bids [1025,3073): keys [D][E][H] f32 -> kT [E][H][D] bf16 (64x64 tiles). Never waits.
// DEADLOCK-FREE under ANY dispatch order: spinners (1024) < residency capacity
// (8 blocks/CU x 256 CU = 2048); route and kT blocks never wait, so slots always drain
// until route runs and releases the flag. (values transpose stays fused in pass0.)
__global__ __launch_bounds__(256) void prep_kernel(
    const float* __restrict__ x,
    const int* __restrict__ idx, const float* __restrict__ wts,
    int* cnt, int* offs, int* rowt, int* pos, float* wrow, int* flag,
    unsigned short* __restrict__ Xg,
    const float* __restrict__ keys, unsigned short* __restrict__ kT) {
  int bid = blockIdx.x;
  int tid = threadIdx.x;

  if (bid == 0) {
    // -------- routing --------
    __shared__ int s_cnt[EE], s_off[EE], s_fill[EE];
    if (tid < EE) s_cnt[tid] = 0;
    __syncthreads();
    for (int i = tid; i < TK; i += 256) atomicAdd(&s_cnt[idx[i]], 1);
    __syncthreads();
    if (tid == 0) {
      int acc = 0;
      for (int e = 0; e < EE; ++e) { s_off[e] = acc; acc += s_cnt[e]; s_fill[e] = s_off[e]; }
    }
    __syncthreads();
    for (int i = tid; i < TK; i += 256) {
      int e = idx[i];
      int r = atomicAdd(&s_fill[e], 1);
      rowt[r] = i;
      pos[i]  = r;
      wrow[r] = wts[i];
    }
    if (tid < EE) { cnt[tid] = s_cnt[tid]; offs[tid] = s_off[tid]; }
    __syncthreads();              // all stores issued (vmcnt drained)
    __threadfence();              // device-scope release: write back to coherent point
    if (tid == 0) atomicExch(flag, 1);
    return;
  }

  if (bid <= 1024) {
    // -------- gather x -> Xg (routed order) --------
    int gbid = bid - 1;
    __shared__ int s_rowt[4];
    if (tid == 0) {
      while (atomicAdd(flag, 0) == 0) __builtin_amdgcn_s_sleep(8);  // acquire spin
    }
    __syncthreads();
    if (tid < 4) s_rowt[tid] = atomicAdd(&rowt[gbid * 4 + tid], 0); // coherent loads
    __syncthreads();
    int i = gbid * 256 + tid;
    int r = i >> 6;               // global routed row (4 per block)
    int c = i & 63;               // DD/8 = 64 chunks per row
    int t = s_rowt[tid >> 6] >> 1;  // KSEL = 2
    const float4* src = (const float4*)(x + (size_t)t * DD + c * 8);
    float4 a = src[0], b = src[1];
    unsigned short res[8];
    res[0]=f2bf(a.x); res[1]=f2bf(a.y); res[2]=f2bf(a.z); res[3]=f2bf(a.w);
    res[4]=f2bf(b.x); res[5]=f2bf(b.y); res[6]=f2bf(b.z); res[7]=f2bf(b.w);
    *(uint4*)(Xg + (size_t)r * DD + c * 8) = *(uint4*)res;
    return;
  }

  // -------- keys transpose: k=d (8 blocks), n=h (32 blocks), 256 blocks/expert --------
  __shared__ unsigned short tt[64][66];
  int rel = bid - 1025; int e = rel >> 8; int rem = rel & 255;
  int k0 = (rem >> 5) * 64, n0 = (rem & 31) * 64;
  #pragma unroll
  for (int it = 0; it < 4; ++it) {
    int id2 = tid + it * 256;
    int r  = id2 >> 4;
    int c4 = id2 & 15;
    float4 v = *(const float4*)(keys + (size_t)(k0 + r) * (EE * HH) + (size_t)e * HH + n0 + c4 * 4);
    unsigned short q[4] = {f2bf(v.x), f2bf(v.y), f2bf(v.z), f2bf(v.w)};
    *(uint2*)&tt[r][c4 * 4] = *(uint2*)q;
  }
  __syncthreads();
  #pragma unroll
  for (int it = 0; it < 2; ++it) {
    int id2 = tid + it * 256;
    int n  = id2 >> 3;
    int kc = (id2 & 7) * 8;
    unsigned short q[8];
    #pragma unroll
    for (int i = 0; i < 8; ++i) q[i] = tt[kc + i][n];
    *(uint4*)(kT + ((size_t)e * HH + n0 + n) * DD + k0 + kc) = *(uint4*)q;
  }
}

// ---------------- values transpose (fused into pass0 grid, LEADING blocks) ----------------
// Leading = prefetch (R6 vs R8 A/B: leading beats trailing by ~4 us).
// nontemporal LOAD (f32 values, read-once stream); NORMAL store so vT stays cached for p1.
__device__ __forceinline__ void vt_transpose(unsigned short* smem, const float* __restrict__ values,
                                             unsigned short* __restrict__ vT, int bid, int tid) {
  // values [H][E][D] f32 -> vT [E][D][H] bf16 ; 2048 blocks, 256/expert (e = bid&7 -> own XCD)
  int e = bid & 7, rem = bid >> 3;
  int k0 = (rem >> 3) * 64;   // h-block (32)
  int n0 = (rem & 7) * 64;    // d-block (8)
  unsigned short (*tt)[66] = (unsigned short(*)[66])smem;
  #pragma unroll
  for (int it = 0; it < 4; ++it) {
    int idx = tid + it * 256;
    int r = idx >> 4, c4 = idx & 15;
    const f32x4* sp = (const f32x4*)(values + (size_t)(k0 + r) * (EE * DD) + (size_t)e * DD + n0 + c4 * 4);
    f32x4 v = __builtin_nontemporal_load(sp);
    unsigned short q[4] = {f2bf(v.x), f2bf(v.y), f2bf(v.z), f2bf(v.w)};
    *(uint2*)&tt[r][c4 * 4] = *(uint2*)q;
  }
  __syncthreads();
  #pragma unroll
  for (int it = 0; it < 2; ++it) {
    int idx = tid + it * 256;
    int n = idx >> 3;
    int kc = (idx & 7) * 8;
    unsigned short q[8];
    #pragma unroll
    for (int i = 0; i < 8; ++i) q[i] = tt[kc + i][n];
    *(uint4*)(vT + ((size_t)e * DD + n0 + n) * HH + k0 + kc) = *(uint4*)q;
  }
}

// ---------------- swizzled global->LDS staging (linear dest, pre-swizzled source) ----------------
// Tile: ROWS x 64 bf16 (128 B/row). LDS(row, slot) holds global (row, slot^(row&7)).
template<int ROWS>
__device__ __forceinline__ void stage_swz(const char* src, int src_stride,
                                          unsigned short* lds, int wave, int lane) {
  constexpr int PW = ROWS * 128 / 1024 / 4;   // insts per wave (4 waves)
  #pragma unroll
  for (int j = 0; j < PW; ++j) {
    int base = (wave * PW + j) * 1024;
    int o = base + lane * 16;
    int row  = o >> 7;
    int slot = (o >> 4) & 7;
    const char* g = src + (size_t)row * src_stride + ((slot ^ (row & 7)) << 4);
    __builtin_amdgcn_global_load_lds(
        (const __attribute__((address_space(1))) unsigned*)g,
        (__attribute__((address_space(3))) unsigned*)((char*)lds + base), 16, 0, 0);
  }
}

// ---------------- grouped expert GEMM body: 64x64 tiles, max TLP, 2-phase dbuf ----------------
// PASS 0: hidden = gelu(Xg @ kT[e]^T + key_bias[e])      bf16 out, K=512,  N=2048
// PASS 1: contrib = (hid @ vT[e]^T [+ bias]) * w         bf16 out, K=2048 (split 2, INTERLEAVED)
// 64x64 tile, 4 waves (2x2, each 32x32 via 2x2 16x16 frags), BK=64.
// LDS 2 x 16 KB = 32 KB/block -> 5 blocks/CU (20 waves/CU). Tile-size curve measured
// (R6/R7/R10): 64^2=41.6 < 64x128=47.9 < 128^2=62 us — fixed LDS/CU conserves
// intensity x concurrency; at NT=8 concurrency wins. 64^2 is the local optimum.
// Per-XCD ordering: e = XCD; within XCD rem = (mblk, xblk, ks) with ks FASTEST so all
// k-split blocks run concurrently (no sequential ks phases).
template<int BM, int BN, int PASS, int KSPLIT>
__device__ __forceinline__ void ffn_gemm_body(
    int bid, unsigned short* smem,
    const unsigned short* __restrict__ Aall, const unsigned short* __restrict__ Bw,
    const float* __restrict__ bias,
    const int* __restrict__ cnt, const int* __restrict__ offs,
    const float* __restrict__ wrow,
    unsigned short* __restrict__ outA, unsigned short* __restrict__ outB)
{
  constexpr int KDIM = (PASS == 0) ? DD : HH;
  constexpr int NDIM = (PASS == 0) ? HH : DD;
  constexpr int KLEN = KDIM / KSPLIT;
  constexpr int NT   = KLEN / 64;
  constexpr int NX   = NDIM / BN;
  constexpr int NY   = TK / BM;
  constexpr int PER_E = NY * NX * KSPLIT;     // blocks per expert
  constexpr int NWG  = EE * PER_E;
  constexpr int WM = BM / 2, WN = BN / 2;
  constexpr int FM = WM / 16, FN = WN / 16;

  // bijective XCD-chunk swizzle (EE==8): XCD owns expert e = bid&7
  int swz = (bid & 7) * (NWG / 8) + (bid >> 3);
  int e   = swz / PER_E;
  int rem = swz % PER_E;
  int mblk = rem / (NX * KSPLIT);
  int r2   = rem % (NX * KSPLIT);
  int xblk = r2 / KSPLIT;
  int ks   = r2 % KSPLIT;

  const int n_e = cnt[e];
  if (mblk * BM >= n_e) return;
  const int off_e = offs[e];
  const int bn = xblk * BN;

  unsigned short* Sb0 = smem;
  unsigned short* Sb1 = smem + (BM + BN) * 64;

  const int tid  = threadIdx.x;
  const int lane = tid & 63;
  const int wave = tid >> 6;
  const int wm = wave >> 1, wn = wave & 1;
  const int lr = lane & 15;
  const int kg = lane >> 4;

  const char* Ab = (const char*)(Aall + (size_t)(off_e + mblk * BM) * KDIM + ks * KLEN);
  const char* Bb = (const char*)(Bw + ((size_t)e * NDIM + bn) * KDIM + ks * KLEN);

  f32x4 acc[FM][FN] = {};

  auto STAGE = [&](unsigned short* buf, int kt) {
    stage_swz<BM>(Ab + kt * 128, KDIM * 2, buf, wave, lane);
    stage_swz<BN>(Bb + kt * 128, KDIM * 2, buf + BM * 64, wave, lane);
  };
  auto COMPUTE = [&](const unsigned short* buf) {
    const char* As = (const char*)buf;
    const char* Bs = (const char*)(buf + BM * 64);
    #pragma unroll
    for (int kss = 0; kss < 2; ++kss) {
      bf16x8 af[FM], bfv[FN];
      #pragma unroll
      for (int fm = 0; fm < FM; ++fm) {
        int r = wm * WM + fm * 16 + lr;
        int sl = (kss * 4 + kg) ^ (r & 7);
        af[fm] = *(const bf16x8*)(As + r * 128 + (sl << 4));
      }
      #pragma unroll
      for (int fn = 0; fn < FN; ++fn) {
        int r = wn * WN + fn * 16 + lr;
        int sl = (kss * 4 + kg) ^ (r & 7);
        bfv[fn] = *(const bf16x8*)(Bs + r * 128 + (sl << 4));
      }
      #pragma unroll
      for (int fm = 0; fm < FM; ++fm)
        #pragma unroll
        for (int fn = 0; fn < FN; ++fn)
          acc[fm][fn] = __builtin_amdgcn_mfma_f32_16x16x32_bf16(af[fm], bfv[fn], acc[fm][fn], 0, 0, 0);
    }
  };

  STAGE(Sb0, 0);
  __syncthreads();
  #pragma unroll 2
  for (int kt = 0; kt < NT; kt += 2) {
    if (kt + 1 < NT) STAGE(Sb1, kt + 1);   // issue next-tile loads BEFORE compute
    COMPUTE(Sb0);
    __syncthreads();
    if (kt + 2 < NT) STAGE(Sb0, kt + 2);
    COMPUTE(Sb1);
    __syncthreads();
  }

  // epilogue
  const int rq = kg * 4;
  #pragma unroll
  for (int fm = 0; fm < FM; ++fm) {
    int row0 = mblk * BM + wm * WM + fm * 16 + rq;
    #pragma unroll
    for (int fn = 0; fn < FN; ++fn) {
      int col = bn + wn * WN + fn * 16 + lr;
      float bs = (PASS == 0 || ks == 0) ? bias[e * NDIM + col] : 0.f;
      #pragma unroll
      for (int i = 0; i < 4; ++i) {
        int rl = row0 + i;
        if (rl < n_e) {
          float v = acc[fm][fn][i] + bs;
          if (PASS == 0) {
            float u = 0.7978845608f * (v + 0.044715f * v * v * v);
            float g = v / (1.f + __expf(-2.f * u));
            outA[(size_t)(off_e + rl) * HH + col] = f2bf(g);
          } else {
            float w = wrow[off_e + rl];
            outB[ks * CONTRIB_ELEMS + (size_t)(off_e + rl) * DD + col] = f2bf(v * w);
          }
        }
      }
    }
  }
}

// Distinct names so rocprof attributes time per pass.
// p0: 2048 vt blocks LEADING (prefetch), then 16384 64x64 GEMM blocks (8/CU at 5/CU resident).
__global__ __launch_bounds__(256, 5) void ffn_gemm_p0(
    const unsigned short* __restrict__ Aall, const unsigned short* __restrict__ Bw,
    const float* __restrict__ bias, const int* __restrict__ cnt, const int* __restrict__ offs,
    const float* __restrict__ wrow, unsigned short* __restrict__ outA,
    const float* __restrict__ values, unsigned short* __restrict__ vT) {
  __shared__ __align__(1024) unsigned short smem[2 * (64 + 64) * 64];
  int bid = blockIdx.x;
  if (bid < 2048) { vt_transpose(smem, values, vT, bid, threadIdx.x); return; }
  ffn_gemm_body<64, 64, 0, 1>(bid - 2048, smem, Aall, Bw, bias, cnt, offs, wrow,
                              outA, nullptr);
}
// p1: 64x64, KSPLIT=2 interleaved (R6-proven), 5 blocks/CU resident, ~128 active/XCD.
__global__ __launch_bounds__(256, 5) void ffn_gemm_p1(
    const unsigned short* __restrict__ Aall, const unsigned short* __restrict__ Bw,
    const float* __restrict__ bias, const int* __restrict__ cnt, const int* __restrict__ offs,
    const float* __restrict__ wrow, unsigned short* __restrict__ outB) {
  __shared__ __align__(1024) unsigned short smem[2 * (64 + 64) * 64];
  ffn_gemm_body<64, 64, 1, KSPLIT1>(blockIdx.x, smem, Aall, Bw, bias, cnt, offs, wrow,
                                    nullptr, outB);
}

// ---------------- combine: out[t] = sum over KSPLIT1 parts and both selected rows ----------------
__global__ void combine(const unsigned short* __restrict__ contrib, const int* __restrict__ pos,
                        float* __restrict__ out) {
  int i = blockIdx.x * blockDim.x + threadIdx.x;   // TB * 64 threads
  int t = i >> 6;
  int c = i & 63;              // 8-elem chunk
  int r0 = pos[t * 2], r1 = pos[t * 2 + 1];
  float o[8] = {0,0,0,0,0,0,0,0};
  #pragma unroll
  for (int p = 0; p < KSPLIT1; ++p) {
    const unsigned short* base = contrib + (size_t)p * CONTRIB_ELEMS;
    union { uint4 q; unsigned short h[8]; } a, b;
    a.q = *(const uint4*)(base + (size_t)r0 * DD + c * 8);
    b.q = *(const uint4*)(base + (size_t)r1 * DD + c * 8);
    #pragma unroll
    for (int j = 0; j < 8; ++j)
      o[j] += bf2f(a.h[j]) + bf2f(b.h[j]);
  }
  float* dst = out + (size_t)t * DD + c * 8;
  *(float4*)dst       = *(float4*)&o[0];
  *(float4*)(dst + 4) = *(float4*)&o[4];
}

extern "C" void kernel_launch(void* const* d_in, const int* in_sizes, int n_in,
                              void* d_out, int out_size, void* d_ws, size_t ws_size,
                              hipStream_t stream) {
  const float* x          = (const float*)d_in[0];
  const int*   indices    = (const int*)d_in[1];
  const float* weights    = (const float*)d_in[2];
  const float* keys       = (const float*)d_in[3];
  const float* key_bias   = (const float*)d_in[4];
  const float* values     = (const float*)d_in[5];
  const float* value_bias = (const float*)d_in[6];
  float* out = (float*)d_out;

  char* ws = (char*)d_ws;
  int*   cnt  = (int*)(ws);
  int*   flag = (int*)(ws + 128);
  int*   offs = (int*)(ws + 256);
  int*   rowt = (int*)(ws + 512);
  int*   pos  = (int*)(ws + 512 + 4 * TK);
  float* wrow = (float*)(ws + 512 + 8 * TK);
  // Xg:  64 KB .. +4.3 MB (+slack)   hid: 8 MB .. +17.0 MB (+slack)
  // kT:  26 MB .. +16.8 MB (dead after pass0; contrib overlays it)
  // vT:  43 MB .. +16.8 MB           contrib: 26 MB .. +8.4 MB (2 x bf16 parts)
  unsigned short* Xg      = (unsigned short*)(ws + (64u << 10));
  unsigned short* hid     = (unsigned short*)(ws + (8u  << 20));
  unsigned short* kT      = (unsigned short*)(ws + (26u << 20));
  unsigned short* vT      = (unsigned short*)(ws + (43u << 20));
  unsigned short* contrib = (unsigned short*)(ws + (26u << 20));

  // zero the release flag (workspace is re-poisoned between runs)
  hipMemsetAsync(flag, 0, 4, stream);

  // prep: 1 route block + 1024 gather blocks (spin-acquire) + 2048 keys-transpose blocks
  prep_kernel<<<3073, 256, 0, stream>>>(x, indices, weights, cnt, offs, rowt, pos, wrow,
                                        flag, Xg, keys, kT);

  // pass 0: 2048 leading vt blocks (values streamed via nt-load) + 16384 GEMM wgs
  //         (64x64, 8/CU work at 5/CU resident)
  ffn_gemm_p0<<<2048 + EE * (TK/64) * (HH/64), 256, 0, stream>>>(
      Xg, kT, key_bias, cnt, offs, wrow, hid, values, vT);
  // pass 1: 64x64, K-split 2 INTERLEAVED (ks fastest)
  ffn_gemm_p1<<<EE * (TK/64) * (DD/64) * KSPLIT1, 256, 0, stream>>>(
      hid, vT, value_bias, cnt, offs, wrow, contrib);
  combine<<<(TB * 64) / 256, 256, 0, stream>>>(contrib, pos, out);
}

// Round 12
// 81.766 us; speedup vs baseline: 1.0760x; 1.0554x over previous
//
#include <hip/hip_runtime.h>
#include <hip/hip_bf16.h>

// Problem constants (B=2,S=1024,D=512,H=2048,E=8,K=2)
#define TB   2048
#define DD   512
#define HH   2048
#define EE   8
#define TK   4096   // TB*KSEL

typedef __attribute__((ext_vector_type(8))) __bf16 bf16x8;
typedef __attribute__((ext_vector_type(4))) float  f32x4;
typedef __attribute__((ext_vector_type(4))) unsigned int u32x4;

#define CONTRIB_ELEMS ((size_t)TK * DD)   // per-ksplit contrib (bf16)
#define KSPLIT1 2                         // pass-1 K-split, ks-interleaved (all concurrent)

__device__ __forceinline__ unsigned short f2bf(float f) {
  return __builtin_bit_cast(unsigned short, (__bf16)f);   // native v_cvt (RNE)
}
__device__ __forceinline__ float bf2f(unsigned short h) {
  union { unsigned u; float f; } c; c.u = (unsigned)h << 16; return c.f;
}

// ---------------- routing ----------------
__global__ void route_kernel(const int* __restrict__ idx, const float* __restrict__ wts,
                             int* cnt, int* offs, int* rowt, int* pos, float* wrow) {
  __shared__ int s_cnt[EE], s_off[EE], s_fill[EE];
  int tid = threadIdx.x;
  if (tid < EE) s_cnt[tid] = 0;
  __syncthreads();
  for (int i = tid; i < TK; i += 256) atomicAdd(&s_cnt[idx[i]], 1);
  __syncthreads();
  if (tid == 0) {
    int acc = 0;
    for (int e = 0; e < EE; ++e) { s_off[e] = acc; acc += s_cnt[e]; s_fill[e] = s_off[e]; }
  }
  __syncthreads();
  for (int i = tid; i < TK; i += 256) {
    int e = idx[i];
    int r = atomicAdd(&s_fill[e], 1);
    rowt[r] = i;
    pos[i]  = r;
    wrow[r] = wts[i];
  }
  if (tid < EE) { cnt[tid] = s_cnt[tid]; offs[tid] = s_off[tid]; }
}

// ---------------- prep: gather-x + keys transpose ----------------
// blocks [0,1024): gather x rows -> Xg (bf16, routed order)
// blocks [1024,3072): keys [D][E][H] f32 -> kT [E][H][D] bf16   (64x64 tiles)
// (values transpose fused into pass0's grid — it is not needed until pass1)
__global__ __launch_bounds__(256) void prep_kernel(
    const float* __restrict__ x, const int* __restrict__ rowt, unsigned short* __restrict__ Xg,
    const float* __restrict__ keys, unsigned short* __restrict__ kT) {
  int bid = blockIdx.x;
  int tid = threadIdx.x;
  if (bid < 1024) {
    int i = bid * 256 + tid;
    int r = i >> 6;            // DD/8 = 64 chunks per row
    int c = i & 63;
    int t = rowt[r] >> 1;      // KSEL = 2
    const float4* src = (const float4*)(x + (size_t)t * DD + c * 8);
    float4 a = src[0], b = src[1];
    unsigned short res[8];
    res[0]=f2bf(a.x); res[1]=f2bf(a.y); res[2]=f2bf(a.z); res[3]=f2bf(a.w);
    res[4]=f2bf(b.x); res[5]=f2bf(b.y); res[6]=f2bf(b.z); res[7]=f2bf(b.w);
    *(uint4*)(Xg + (size_t)r * DD + c * 8) = *(uint4*)res;
    return;
  }
  __shared__ unsigned short tt[64][66];
  // keys: k=d (8 blocks), n=h (32 blocks), 256 blocks/expert
  int rel = bid - 1024; int e = rel >> 8; int rem = rel & 255;
  int k0 = (rem >> 5) * 64, n0 = (rem & 31) * 64;
  #pragma unroll
  for (int it = 0; it < 4; ++it) {
    int idx = tid + it * 256;
    int r  = idx >> 4;
    int c4 = idx & 15;
    float4 v = *(const float4*)(keys + (size_t)(k0 + r) * (EE * HH) + (size_t)e * HH + n0 + c4 * 4);
    unsigned short q[4] = {f2bf(v.x), f2bf(v.y), f2bf(v.z), f2bf(v.w)};
    *(uint2*)&tt[r][c4 * 4] = *(uint2*)q;
  }
  __syncthreads();
  #pragma unroll
  for (int it = 0; it < 2; ++it) {
    int idx = tid + it * 256;
    int n  = idx >> 3;
    int kc = (idx & 7) * 8;
    unsigned short q[8];
    #pragma unroll
    for (int i = 0; i < 8; ++i) q[i] = tt[kc + i][n];
    *(uint4*)(kT + ((size_t)e * HH + n0 + n) * DD + k0 + kc) = *(uint4*)q;
  }
}

// ---------------- values transpose (fused into pass0 grid, LEADING blocks) ----------------
// Leading = prefetch: short streaming blocks drain into GEMM with traffic still in flight
// (R6 vs R8 A/B: leading beats trailing by ~4 us).
// nontemporal LOAD (f32 values, read-once stream); NORMAL store so vT stays cached for p1.
__device__ __forceinline__ void vt_transpose(unsigned short* smem, const float* __restrict__ values,
                                             unsigned short* __restrict__ vT, int bid, int tid) {
  // values [H][E][D] f32 -> vT [E][D][H] bf16 ; 2048 blocks, 256/expert (e = bid&7 -> own XCD)
  int e = bid & 7, rem = bid >> 3;
  int k0 = (rem >> 3) * 64;   // h-block (32)
  int n0 = (rem & 7) * 64;    // d-block (8)
  unsigned short (*tt)[66] = (unsigned short(*)[66])smem;
  #pragma unroll
  for (int it = 0; it < 4; ++it) {
    int idx = tid + it * 256;
    int r = idx >> 4, c4 = idx & 15;
    const f32x4* sp = (const f32x4*)(values + (size_t)(k0 + r) * (EE * DD) + (size_t)e * DD + n0 + c4 * 4);
    f32x4 v = __builtin_nontemporal_load(sp);
    unsigned short q[4] = {f2bf(v.x), f2bf(v.y), f2bf(v.z), f2bf(v.w)};
    *(uint2*)&tt[r][c4 * 4] = *(uint2*)q;
  }
  __syncthreads();
  #pragma unroll
  for (int it = 0; it < 2; ++it) {
    int idx = tid + it * 256;
    int n = idx >> 3;
    int kc = (idx & 7) * 8;
    unsigned short q[8];
    #pragma unroll
    for (int i = 0; i < 8; ++i) q[i] = tt[kc + i][n];
    *(uint4*)(vT + ((size_t)e * DD + n0 + n) * HH + k0 + kc) = *(uint4*)q;
  }
}

// ---------------- swizzled global->LDS staging (linear dest, pre-swizzled source) ----------------
// Tile: ROWS x 64 bf16 (128 B/row). LDS(row, slot) holds global (row, slot^(row&7)).
template<int ROWS>
__device__ __forceinline__ void stage_swz(const char* src, int src_stride,
                                          unsigned short* lds, int wave, int lane) {
  constexpr int PW = ROWS * 128 / 1024 / 4;   // insts per wave (4 waves)
  #pragma unroll
  for (int j = 0; j < PW; ++j) {
    int base = (wave * PW + j) * 1024;
    int o = base + lane * 16;
    int row  = o >> 7;
    int slot = (o >> 4) & 7;
    const char* g = src + (size_t)row * src_stride + ((slot ^ (row & 7)) << 4);
    __builtin_amdgcn_global_load_lds(
        (const __attribute__((address_space(1))) unsigned*)g,
        (__attribute__((address_space(3))) unsigned*)((char*)lds + base), 16, 0, 0);
  }
}

// ---------------- grouped expert GEMM body: 64x64 tiles, max TLP, 2-phase dbuf ----------------
// PASS 0: hidden = gelu(Xg @ kT[e]^T + key_bias[e])      bf16 out, K=512,  N=2048
// PASS 1: contrib = (hid @ vT[e]^T [+ bias]) * w         bf16 out, K=2048 (split 2, INTERLEAVED)
// 64x64 tile, 4 waves (2x2, each 32x32 via 2x2 16x16 frags), BK=64.
// LDS 2 x 16 KB = 32 KB/block -> 5 blocks/CU (20 waves/CU). Tile-size curve measured
// (R6/R7/R10): 64^2=41.6 < 64x128=47.9 < 128^2=62 us — fixed LDS/CU conserves
// intensity x concurrency; at NT=8 concurrency wins. 64^2 is the local optimum.
// Per-XCD ordering: e = XCD; within XCD rem = (mblk, xblk, ks) with ks FASTEST so all
// k-split blocks run concurrently (no sequential ks phases).
template<int BM, int BN, int PASS, int KSPLIT>
__device__ __forceinline__ void ffn_gemm_body(
    int bid, unsigned short* smem,
    const unsigned short* __restrict__ Aall, const unsigned short* __restrict__ Bw,
    const float* __restrict__ bias,
    const int* __restrict__ cnt, const int* __restrict__ offs,
    const float* __restrict__ wrow,
    unsigned short* __restrict__ outA, unsigned short* __restrict__ outB)
{
  constexpr int KDIM = (PASS == 0) ? DD : HH;
  constexpr int NDIM = (PASS == 0) ? HH : DD;
  constexpr int KLEN = KDIM / KSPLIT;
  constexpr int NT   = KLEN / 64;             // 8 (pass0) / 16 (pass1 KS2)
  constexpr int NX   = NDIM / BN;
  constexpr int NY   = TK / BM;
  constexpr int PER_E = NY * NX * KSPLIT;     // blocks per expert
  constexpr int NWG  = EE * PER_E;
  constexpr int WM = BM / 2, WN = BN / 2;
  constexpr int FM = WM / 16, FN = WN / 16;

  // bijective XCD-chunk swizzle (EE==8): XCD owns expert e = bid&7
  int swz = (bid & 7) * (NWG / 8) + (bid >> 3);
  int e   = swz / PER_E;
  int rem = swz % PER_E;
  int mblk = rem / (NX * KSPLIT);
  int r2   = rem % (NX * KSPLIT);
  int xblk = r2 / KSPLIT;
  int ks   = r2 % KSPLIT;

  const int n_e = cnt[e];
  if (mblk * BM >= n_e) return;
  const int off_e = offs[e];
  const int bn = xblk * BN;

  unsigned short* Sb0 = smem;
  unsigned short* Sb1 = smem + (BM + BN) * 64;

  const int tid  = threadIdx.x;
  const int lane = tid & 63;
  const int wave = tid >> 6;
  const int wm = wave >> 1, wn = wave & 1;
  const int lr = lane & 15;
  const int kg = lane >> 4;

  const char* Ab = (const char*)(Aall + (size_t)(off_e + mblk * BM) * KDIM + ks * KLEN);
  const char* Bb = (const char*)(Bw + ((size_t)e * NDIM + bn) * KDIM + ks * KLEN);

  f32x4 acc[FM][FN] = {};

  auto STAGE = [&](unsigned short* buf, int kt) {
    stage_swz<BM>(Ab + kt * 128, KDIM * 2, buf, wave, lane);
    stage_swz<BN>(Bb + kt * 128, KDIM * 2, buf + BM * 64, wave, lane);
  };
  auto COMPUTE = [&](const unsigned short* buf) {
    const char* As = (const char*)buf;
    const char* Bs = (const char*)(buf + BM * 64);
    #pragma unroll
    for (int kss = 0; kss < 2; ++kss) {
      bf16x8 af[FM], bfv[FN];
      #pragma unroll
      for (int fm = 0; fm < FM; ++fm) {
        int r = wm * WM + fm * 16 + lr;
        int sl = (kss * 4 + kg) ^ (r & 7);
        af[fm] = *(const bf16x8*)(As + r * 128 + (sl << 4));
      }
      #pragma unroll
      for (int fn = 0; fn < FN; ++fn) {
        int r = wn * WN + fn * 16 + lr;
        int sl = (kss * 4 + kg) ^ (r & 7);
        bfv[fn] = *(const bf16x8*)(Bs + r * 128 + (sl << 4));
      }
      #pragma unroll
      for (int fm = 0; fm < FM; ++fm)
        #pragma unroll
        for (int fn = 0; fn < FN; ++fn)
          acc[fm][fn] = __builtin_amdgcn_mfma_f32_16x16x32_bf16(af[fm], bfv[fn], acc[fm][fn], 0, 0, 0);
    }
  };

  STAGE(Sb0, 0);
  __syncthreads();
  #pragma unroll 2
  for (int kt = 0; kt < NT; kt += 2) {
    if (kt + 1 < NT) STAGE(Sb1, kt + 1);   // issue next-tile loads BEFORE compute
    COMPUTE(Sb0);
    __syncthreads();
    if (kt + 2 < NT) STAGE(Sb0, kt + 2);
    COMPUTE(Sb1);
    __syncthreads();
  }

  // epilogue
  const int rq = kg * 4;
  #pragma unroll
  for (int fm = 0; fm < FM; ++fm) {
    int row0 = mblk * BM + wm * WM + fm * 16 + rq;
    #pragma unroll
    for (int fn = 0; fn < FN; ++fn) {
      int col = bn + wn * WN + fn * 16 + lr;
      float bs = (PASS == 0 || ks == 0) ? bias[e * NDIM + col] : 0.f;
      #pragma unroll
      for (int i = 0; i < 4; ++i) {
        int rl = row0 + i;
        if (rl < n_e) {
          float v = acc[fm][fn][i] + bs;
          if (PASS == 0) {
            float u = 0.7978845608f * (v + 0.044715f * v * v * v);
            float g = v / (1.f + __expf(-2.f * u));
            outA[(size_t)(off_e + rl) * HH + col] = f2bf(g);
          } else {
            float w = wrow[off_e + rl];
            outB[ks * CONTRIB_ELEMS + (size_t)(off_e + rl) * DD + col] = f2bf(v * w);
          }
        }
      }
    }
  }
}

// Distinct names so rocprof attributes time per pass.
__global__ __launch_bounds__(256, 5) void ffn_gemm_p0(
    const unsigned short* __restrict__ Aall, const unsigned short* __restrict__ Bw,
    const float* __restrict__ bias, const int* __restrict__ cnt, const int* __restrict__ offs,
    const float* __restrict__ wrow, unsigned short* __restrict__ outA,
    const float* __restrict__ values, unsigned short* __restrict__ vT) {
  __shared__ __align__(1024) unsigned short smem[2 * (64 + 64) * 64];
  int bid = blockIdx.x;
  if (bid < 2048) { vt_transpose(smem, values, vT, bid, threadIdx.x); return; }
  ffn_gemm_body<64, 64, 0, 1>(bid - 2048, smem, Aall, Bw, bias, cnt, offs, wrow,
                              outA, nullptr);
}
__global__ __launch_bounds__(256, 5) void ffn_gemm_p1(
    const unsigned short* __restrict__ Aall, const unsigned short* __restrict__ Bw,
    const float* __restrict__ bias, const int* __restrict__ cnt, const int* __restrict__ offs,
    const float* __restrict__ wrow, unsigned short* __restrict__ outB) {
  __shared__ __align__(1024) unsigned short smem[2 * (64 + 64) * 64];
  ffn_gemm_body<64, 64, 1, KSPLIT1>(blockIdx.x, smem, Aall, Bw, bias, cnt, offs, wrow,
                                    nullptr, outB);
}

// ---------------- combine: out[t] = sum over KSPLIT1 parts and both selected rows ----------------
__global__ void combine(const unsigned short* __restrict__ contrib, const int* __restrict__ pos,
                        float* __restrict__ out) {
  int i = blockIdx.x * blockDim.x + threadIdx.x;   // TB * 64 threads
  int t = i >> 6;
  int c = i & 63;              // 8-elem chunk
  int r0 = pos[t * 2], r1 = pos[t * 2 + 1];
  float o[8] = {0,0,0,0,0,0,0,0};
  #pragma unroll
  for (int p = 0; p < KSPLIT1; ++p) {
    const unsigned short* base = contrib + (size_t)p * CONTRIB_ELEMS;
    union { uint4 q; unsigned short h[8]; } a, b;
    a.q = *(const uint4*)(base + (size_t)r0 * DD + c * 8);
    b.q = *(const uint4*)(base + (size_t)r1 * DD + c * 8);
    #pragma unroll
    for (int j = 0; j < 8; ++j)
      o[j] += bf2f(a.h[j]) + bf2f(b.h[j]);
  }
  float* dst = out + (size_t)t * DD + c * 8;
  *(float4*)dst       = *(float4*)&o[0];
  *(float4*)(dst + 4) = *(float4*)&o[4];
}

extern "C" void kernel_launch(void* const* d_in, const int* in_sizes, int n_in,
                              void* d_out, int out_size, void* d_ws, size_t ws_size,
                              hipStream_t stream) {
  const float* x          = (const float*)d_in[0];
  const int*   indices    = (const int*)d_in[1];
  const float* weights    = (const float*)d_in[2];
  const float* keys       = (const float*)d_in[3];
  const float* key_bias   = (const float*)d_in[4];
  const float* values     = (const float*)d_in[5];
  const float* value_bias = (const float*)d_in[6];
  float* out = (float*)d_out;

  char* ws = (char*)d_ws;
  int*   cnt  = (int*)(ws);
  int*   offs = (int*)(ws + 256);
  int*   rowt = (int*)(ws + 512);
  int*   pos  = (int*)(ws + 512 + 4 * TK);
  float* wrow = (float*)(ws + 512 + 8 * TK);
  // Xg:  64 KB .. +4.3 MB (+slack)   hid: 8 MB .. +17.0 MB (+slack)
  // kT:  26 MB .. +16.8 MB (dead after pass0; contrib overlays it)
  // vT:  43 MB .. +16.8 MB           contrib: 26 MB .. +8.4 MB (2 x bf16 parts)
  unsigned short* Xg      = (unsigned short*)(ws + (64u << 10));
  unsigned short* hid     = (unsigned short*)(ws + (8u  << 20));
  unsigned short* kT      = (unsigned short*)(ws + (26u << 20));
  unsigned short* vT      = (unsigned short*)(ws + (43u << 20));
  unsigned short* contrib = (unsigned short*)(ws + (26u << 20));

  route_kernel<<<1, 256, 0, stream>>>(indices, weights, cnt, offs, rowt, pos, wrow);
  // prep: 1024 gather blocks + 2048 keys-transpose blocks
  prep_kernel<<<3072, 256, 0, stream>>>(x, rowt, Xg, keys, kT);

  // pass 0: 2048 leading vt blocks (values streamed via nt-load) + 16384 GEMM wgs
  //         (64x64, 8/CU work at 5/CU resident)
  ffn_gemm_p0<<<2048 + EE * (TK/64) * (HH/64), 256, 0, stream>>>(
      Xg, kT, key_bias, cnt, offs, wrow, hid, values, vT);
  // pass 1: K-split 2 INTERLEAVED (ks fastest) => ~128 active/XCD = 4/CU concurrent
  ffn_gemm_p1<<<EE * (TK/64) * (DD/64) * KSPLIT1, 256, 0, stream>>>(
      hid, vT, value_bias, cnt, offs, wrow, contrib);
  combine<<<(TB * 64) / 256, 256, 0, stream>>>(contrib, pos, out);
}